// Round 1
// baseline (404.496 us; speedup 1.0000x reference)
//
#include <hip/hip_runtime.h>

typedef __attribute__((ext_vector_type(8))) short short8;
typedef __attribute__((ext_vector_type(4))) short bfx4;
typedef __attribute__((ext_vector_type(4))) float floatx4;

#define N_NODES 20000
#define N_EDGES 160000
#define TILE_E 64
#define EBLK (N_EDGES / TILE_E)   // 2500

#define C0f   0.14433756729740643f   // sqrt(1/48)
#define C1f   0.21650635094610965f   // sqrt(3/64)
#define IS3   0.5773502691896258f    // 1/sqrt(3)
#define IS6   0.4082482904638631f    // 1/sqrt(6)
#define EPS_LN 1e-5f

// ws layout (bytes):
//   [0, 32768)        w1f: W1 bf16, MFMA B-frag order
//   [32768, 688128)   w2f: W2 bf16, MFMA B-frag order
//   [688128, 768128)  cnt: N_NODES floats (zeroed by prep)
#define W1F_OFF 0
#define W2F_OFF 32768
#define CNT_OFF 688128

__device__ __forceinline__ short f2bf(float f) {   // fp32 -> bf16 RNE
    unsigned u = __float_as_uint(f);
    u += 0x7fff + ((u >> 16) & 1);
    return (short)(u >> 16);
}
__device__ __forceinline__ float bf2f(short s) {
    return __uint_as_float(((unsigned)(unsigned short)s) << 16);
}

__device__ __forceinline__ short8 load8_bf16(const float* p) {
    const float4* q = (const float4*)p;
    float4 f0 = q[0], f1 = q[1];
    short8 s;
    s[0]=f2bf(f0.x); s[1]=f2bf(f0.y); s[2]=f2bf(f0.z); s[3]=f2bf(f0.w);
    s[4]=f2bf(f1.x); s[5]=f2bf(f1.y); s[6]=f2bf(f1.z); s[7]=f2bf(f1.w);
    return s;
}

__device__ __forceinline__ floatx4 mfma4(const short8* a, short8 b0, short8 b1,
                                         short8 b2, short8 b3, float bias) {
    floatx4 C = {bias, bias, bias, bias};   // bias as C-init: free bias add
    C = __builtin_amdgcn_mfma_f32_16x16x32_bf16(a[0], b0, C, 0, 0, 0);
    C = __builtin_amdgcn_mfma_f32_16x16x32_bf16(a[1], b1, C, 0, 0, 0);
    C = __builtin_amdgcn_mfma_f32_16x16x32_bf16(a[2], b2, C, 0, 0, 0);
    C = __builtin_amdgcn_mfma_f32_16x16x32_bf16(a[3], b3, C, 0, 0, 0);
    return C;
}

// x-tile LDS swizzle: 4-short granules, granule g' = g ^ (row & 15).
// Writes (per-element) and reads (4-aligned bfx4) both apply it; a wave's
// gather write (consecutive c, ~fixed e) now spreads over 16 banks instead
// of landing on 1-2 (the 128 B row stride == full bank sweep).
__device__ __forceinline__ int xsw(int row, int e) {
    return row * 64 + ((e & 3) | ((((e >> 2) ^ row) & 15) << 2));
}
__device__ __forceinline__ bfx4 ldx(const short* base, int row, int gran) {
    return *(const bfx4*)(base + row * 64 + (((gran ^ row) & 15) << 2));
}

// W1/W2 -> bf16 fragment order; also zero cnt.
__global__ __launch_bounds__(256)
void prep_kernel(const float* __restrict__ fc_w1, const float* __restrict__ fc_w2,
                 short* __restrict__ w1f, short* __restrict__ w2f,
                 float* __restrict__ cnt) {
    int g = blockIdx.x * 256 + threadIdx.x;
    if (g < N_NODES) cnt[g] = 0.0f;
    if (g < 2048) {                      // W1: t<8, kt<4
        int ln = g & 15, qd = (g >> 4) & 3, kt = (g >> 6) & 3, t = g >> 8;
        int n = t * 16 + ln, kb = kt * 32 + qd * 8;
        short8 s;
        #pragma unroll
        for (int j = 0; j < 8; ++j) s[j] = f2bf(fc_w1[(kb + j) * 128 + n]);
        *(short8*)(w1f + g * 8) = s;
        return;
    }
    int g2 = g - 2048;
    if (g2 < 40960) {                    // W2: t<160, kt<4
        int ln = g2 & 15, qd = (g2 >> 4) & 3, kt = (g2 >> 6) & 3, t = g2 >> 8;
        int n = t * 16 + ln, kb = kt * 32 + qd * 8;
        short8 s;
        #pragma unroll
        for (int j = 0; j < 8; ++j) s[j] = f2bf(fc_w2[(kb + j) * 2560 + n]);
        *(short8*)(w2f + g2 * 8) = s;
    }
}

__global__ __launch_bounds__(128, 4)
void edge_kernel(const float* __restrict__ node_attr,
                 const float* __restrict__ edge_attr,
                 const float* __restrict__ edge_sh,
                 const float* __restrict__ fc_b1,
                 const float* __restrict__ fc_b2,
                 const int*   __restrict__ edge_index,
                 const short* __restrict__ w1f,
                 const short* __restrict__ w2f,
                 float* __restrict__ accum,   // d_out, pre-zeroed
                 float* __restrict__ cnt)     // zeroed by prep
{
    // s_H (64x136 shorts, wave-private rows) is dead once a2 frags are in
    // registers; the x-tiles are only written after that point. Overlay them:
    // LDS 31.2 KB -> 18.9 KB, 5 -> 8 blocks/CU.
    __shared__ __align__(16) short s_pool[64 * 136];   // 17408 B
    __shared__ float s_sh[64 * 4];
    __shared__ int   s_src[64];
    __shared__ int   s_dst[64];

    short* s_H    = s_pool;            // [64][136] bf16 hidden activations
    short* s_x0t  = s_pool;            // [32][64] swizzled: [u][e']
    short* s_x1t  = s_pool + 2048;     // [48][64] swizzled: [u*3+i][e']
    short* s_x1dt = s_pool + 5120;     // [16][64] swizzled: [u][e']

    const int tid = threadIdx.x;
    const int e0  = blockIdx.x * TILE_E;

    // ---- phase A: indices, sh ----
    if (tid < 64) {
        int s = edge_index[e0 + tid];
        int d = edge_index[N_EDGES + e0 + tid];
        s_src[tid] = s; s_dst[tid] = d;
        atomicAdd(&cnt[s], 1.0f);
    }
    s_sh[tid]       = edge_sh[(size_t)e0 * 4 + tid];
    s_sh[tid + 128] = edge_sh[(size_t)e0 * 4 + tid + 128];
    __syncthreads();

    // ---- per-wave identity: wave owns 32 edges as 2 MFMA groups ----
    const int lane = tid & 63;
    const int wv   = tid >> 6;
    const int ln   = lane & 15;
    const int qd   = lane >> 4;
    const int eb0  = wv * 32 + qd * 4;        // group 0 C-row base
    const int eb1  = eb0 + 16;                // group 1
    const int gr0  = eb0 >> 2;                // swizzle granules (4-aligned)
    const int gr1  = eb1 >> 2;

    // ---- MLP1: h = relu(EA @ W1 + b1) via MFMA ----
    {
        short8 a1[2][4];
        #pragma unroll
        for (int g = 0; g < 2; ++g) {
            const float* ap = edge_attr + (size_t)(e0 + wv*32 + g*16 + ln) * 128 + qd * 8;
            #pragma unroll
            for (int kt = 0; kt < 4; ++kt) a1[g][kt] = load8_bf16(ap + kt * 32);
        }
        #pragma unroll
        for (int t = 0; t < 8; ++t) {
            const short* bp = w1f + t * 2048 + lane * 8;
            short8 b0 = *(const short8*)bp;
            short8 b1 = *(const short8*)(bp + 512);
            short8 b2 = *(const short8*)(bp + 1024);
            short8 b3 = *(const short8*)(bp + 1536);
            float bias = fc_b1[t * 16 + ln];
            #pragma unroll
            for (int g = 0; g < 2; ++g) {
                floatx4 C = mfma4(a1[g], b0, b1, b2, b3, bias);
                #pragma unroll
                for (int r = 0; r < 4; ++r)
                    s_H[(wv*32 + g*16 + qd*4 + r) * 136 + t*16 + ln] = f2bf(fmaxf(C[r], 0.f));
            }
        }
    }

    // A2 fragments — each wave reads only its own s_H rows (wave-private):
    // no barrier needed before this, compiler's lgkmcnt handles the RAW.
    short8 a2[2][4];
    #pragma unroll
    for (int g = 0; g < 2; ++g) {
        const short* hp = s_H + (wv*32 + g*16 + ln) * 136 + qd * 8;
        #pragma unroll
        for (int kt = 0; kt < 4; ++kt) a2[g][kt] = *(const short8*)(hp + kt * 32);
    }
    __syncthreads();   // ALL waves done reading s_H before x-tiles overwrite it

    // ---- gather (transposed, swizzled bf16) + x1.sh1 dot ----
    #pragma unroll
    for (int i = 0; i < 40; ++i) {
        int f = tid + i * 128;
        int e = f / 80, c = f % 80;
        float v = node_attr[(size_t)s_dst[e] * 80 + c];
        if (c < 32) s_x0t[xsw(c, e)] = f2bf(v);
        else        s_x1t[xsw(c - 32, e)] = f2bf(v);
    }
    #pragma unroll
    for (int i = 0; i < 8; ++i) {
        int it = tid + i * 128;
        int e = it >> 4, u = it & 15;
        const float* xp = node_attr + (size_t)s_dst[e] * 80 + 32 + u * 3;
        float d = xp[0] * s_sh[e*4+1] + xp[1] * s_sh[e*4+2] + xp[2] * s_sh[e*4+3];
        s_x1dt[xsw(u, e)] = f2bf(d);
    }
    __syncthreads();

    const short* wbase = w2f + lane * 8;

    // ================= PHASE 1: out0 (regions 1-2) =================
    float r0lo[2][4] = {}, r0hi[2][4] = {}, r1lo[2][4] = {}, r1hi[2][4] = {};

    #pragma unroll 2
    for (int u = 0; u < 32; ++u) {       // region 1: tiles 2u, 2u+1
        const short* bp = wbase + (size_t)(2*u) * 2048;
        short8 L0 = *(const short8*)bp,          L1 = *(const short8*)(bp + 512);
        short8 L2 = *(const short8*)(bp + 1024), L3 = *(const short8*)(bp + 1536);
        short8 H0 = *(const short8*)(bp + 2048), H1 = *(const short8*)(bp + 2560);
        short8 H2 = *(const short8*)(bp + 3072), H3 = *(const short8*)(bp + 3584);
        float blo = fc_b2[2*u*16 + ln], bhi = fc_b2[2*u*16 + 16 + ln];
        #pragma unroll
        for (int g = 0; g < 2; ++g) {
            floatx4 Clo = mfma4(a2[g], L0, L1, L2, L3, blo);
            floatx4 Chi = mfma4(a2[g], H0, H1, H2, H3, bhi);
            bfx4 xs = ldx(s_x0t, u, g ? gr1 : gr0);
            #pragma unroll
            for (int r = 0; r < 4; ++r) {
                float a = bf2f(xs[r]);
                r0lo[g][r] += a * Clo[r];
                r0hi[g][r] += a * Chi[r];
            }
        }
    }
    #pragma unroll 2
    for (int u = 0; u < 16; ++u) {       // region 2: tiles 64+2u, 65+2u
        const short* bp = wbase + (size_t)(64 + 2*u) * 2048;
        short8 L0 = *(const short8*)bp,          L1 = *(const short8*)(bp + 512);
        short8 L2 = *(const short8*)(bp + 1024), L3 = *(const short8*)(bp + 1536);
        short8 H0 = *(const short8*)(bp + 2048), H1 = *(const short8*)(bp + 2560);
        short8 H2 = *(const short8*)(bp + 3072), H3 = *(const short8*)(bp + 3584);
        float blo = fc_b2[(64 + 2*u)*16 + ln], bhi = fc_b2[(64 + 2*u)*16 + 16 + ln];
        #pragma unroll
        for (int g = 0; g < 2; ++g) {
            floatx4 Clo = mfma4(a2[g], L0, L1, L2, L3, blo);
            floatx4 Chi = mfma4(a2[g], H0, H1, H2, H3, bhi);
            bfx4 xs = ldx(s_x1dt, u, g ? gr1 : gr0);
            #pragma unroll
            for (int r = 0; r < 4; ++r) {
                float a = bf2f(xs[r]);
                r1lo[g][r] += a * Clo[r];
                r1hi[g][r] += a * Chi[r];
            }
        }
    }
    // phase-1 epilogue: out0 scatter
    #pragma unroll
    for (int g = 0; g < 2; ++g)
        #pragma unroll
        for (int r = 0; r < 4; ++r) {
            int e = (g ? eb1 : eb0) + r;
            float sh0 = s_sh[e*4];
            int base = s_src[e] * 80;
            atomicAdd(&accum[base + ln],      C0f * (sh0 * r0lo[g][r] + IS3 * r1lo[g][r]));
            atomicAdd(&accum[base + 16 + ln], C0f * (sh0 * r0hi[g][r] + IS3 * r1hi[g][r]));
        }

    // ================= PHASE 2: out1 (regions 3-5) =================
    float r3[2][4] = {};
    float r4[2][4][3] = {};
    float r5[2][4][3] = {};

    #pragma unroll 2
    for (int u = 0; u < 32; ++u) {       // region 3: tile 96+u
        const short* bp = wbase + (size_t)(96 + u) * 2048;
        short8 b0 = *(const short8*)bp,          b1 = *(const short8*)(bp + 512);
        short8 b2 = *(const short8*)(bp + 1024), b3 = *(const short8*)(bp + 1536);
        float bias = fc_b2[(96 + u)*16 + ln];
        #pragma unroll
        for (int g = 0; g < 2; ++g) {
            floatx4 C = mfma4(a2[g], b0, b1, b2, b3, bias);
            bfx4 xs = ldx(s_x0t, u, g ? gr1 : gr0);
            #pragma unroll
            for (int r = 0; r < 4; ++r)
                r3[g][r] += bf2f(xs[r]) * C[r];
        }
    }
    for (int u = 0; u < 16; ++u) {       // regions 4+5: tiles 128+u, 144+u share x1 reads
        const short* bp4 = wbase + (size_t)(128 + u) * 2048;
        short8 F0 = *(const short8*)bp4,          F1 = *(const short8*)(bp4 + 512);
        short8 F2 = *(const short8*)(bp4 + 1024), F3 = *(const short8*)(bp4 + 1536);
        const short* bp5 = wbase + (size_t)(144 + u) * 2048;
        short8 G0 = *(const short8*)bp5,          G1 = *(const short8*)(bp5 + 512);
        short8 G2 = *(const short8*)(bp5 + 1024), G3 = *(const short8*)(bp5 + 1536);
        float b4 = fc_b2[(128 + u)*16 + ln], b5 = fc_b2[(144 + u)*16 + ln];
        #pragma unroll
        for (int g = 0; g < 2; ++g) {
            floatx4 C4 = mfma4(a2[g], F0, F1, F2, F3, b4);
            floatx4 C5 = mfma4(a2[g], G0, G1, G2, G3, b5);
            int gr = (g ? gr1 : gr0);
            bfx4 x0s = ldx(s_x1t, u*3 + 0, gr);
            bfx4 x1s = ldx(s_x1t, u*3 + 1, gr);
            bfx4 x2s = ldx(s_x1t, u*3 + 2, gr);
            #pragma unroll
            for (int r = 0; r < 4; ++r) {
                float a0 = bf2f(x0s[r]), a1 = bf2f(x1s[r]), a2v = bf2f(x2s[r]);
                r4[g][r][0] += a0 * C4[r];  r5[g][r][0] += a0 * C5[r];
                r4[g][r][1] += a1 * C4[r];  r5[g][r][1] += a1 * C5[r];
                r4[g][r][2] += a2v * C4[r]; r5[g][r][2] += a2v * C5[r];
            }
        }
    }
    // phase-2 epilogue: out1 scatter (region-5 cross applied here; linear in u)
    #pragma unroll
    for (int g = 0; g < 2; ++g)
        #pragma unroll
        for (int r = 0; r < 4; ++r) {
            int e = (g ? eb1 : eb0) + r;
            float sh0 = s_sh[e*4], sa = s_sh[e*4+1], sb = s_sh[e*4+2], sc = s_sh[e*4+3];
            int base = s_src[e] * 80;
            float t3 = C1f * IS3 * r3[g][r];
            float s0 = C1f * IS3 * sh0;
            float c6 = C1f * IS6;
            float v50 = r5[g][r][1] * sc - r5[g][r][2] * sb;
            float v51 = r5[g][r][2] * sa - r5[g][r][0] * sc;
            float v52 = r5[g][r][0] * sb - r5[g][r][1] * sa;
            atomicAdd(&accum[base + 32 + ln*3 + 0], sa * t3 + s0 * r4[g][r][0] + c6 * v50);
            atomicAdd(&accum[base + 32 + ln*3 + 1], sb * t3 + s0 * r4[g][r][1] + c6 * v51);
            atomicAdd(&accum[base + 32 + ln*3 + 2], sc * t3 + s0 * r4[g][r][2] + c6 * v52);
        }
}

// Per-node: mean-divide, residual, equivariant layernorm. In-place on d_out.
__global__ __launch_bounds__(256)
void node_kernel(const float* __restrict__ node_attr,
                 const float* __restrict__ mean_shift,
                 const float* __restrict__ aw,
                 const float* __restrict__ ab,
                 const float* __restrict__ cnt,
                 float* __restrict__ out)
{
    int n = blockIdx.x * blockDim.x + threadIdx.x;
    if (n >= N_NODES) return;
    float inv = 1.0f / fmaxf(cnt[n], 1.0f);
    size_t base = (size_t)n * 80;
    float v[80];
    const float4* o4 = (const float4*)(out + base);
    const float4* a4 = (const float4*)(node_attr + base);
    #pragma unroll
    for (int i = 0; i < 20; ++i) {
        float4 o = o4[i], a = a4[i];
        v[4*i+0] = o.x * inv + a.x;
        v[4*i+1] = o.y * inv + a.y;
        v[4*i+2] = o.z * inv + a.z;
        v[4*i+3] = o.w * inv + a.w;
    }

    float m0 = 0.f;
    #pragma unroll
    for (int u = 0; u < 32; ++u) m0 += v[u];
    m0 *= (1.0f / 32.0f);
    float n0 = 0.f;
    #pragma unroll
    for (int u = 0; u < 32; ++u) {
        float f = v[u] - m0 * mean_shift[u];
        v[u] = f;
        n0 += f * f;
    }
    n0 = rsqrtf(n0 * (1.0f / 32.0f) + EPS_LN);
    #pragma unroll
    for (int u = 0; u < 32; ++u) v[u] = v[u] * (n0 * aw[u]) + ab[u];

    float m1[3] = {0.f, 0.f, 0.f};
    #pragma unroll
    for (int u = 0; u < 16; ++u)
        #pragma unroll
        for (int i = 0; i < 3; ++i) m1[i] += v[32 + u*3 + i];
    #pragma unroll
    for (int i = 0; i < 3; ++i) m1[i] *= (1.0f / 16.0f);
    float n1 = 0.f;
    #pragma unroll
    for (int u = 0; u < 16; ++u)
        #pragma unroll
        for (int i = 0; i < 3; ++i) {
            float f = v[32 + u*3 + i] - m1[i] * mean_shift[32 + u];
            v[32 + u*3 + i] = f;
            n1 += f * f;
        }
    n1 = rsqrtf(n1 * (1.0f / 48.0f) + EPS_LN);
    #pragma unroll
    for (int u = 0; u < 16; ++u)
        #pragma unroll
        for (int i = 0; i < 3; ++i)
            v[32 + u*3 + i] *= (n1 * aw[32 + u]);

    float4* w4 = (float4*)(out + base);
    #pragma unroll
    for (int i = 0; i < 20; ++i) {
        float4 o; o.x = v[4*i]; o.y = v[4*i+1]; o.z = v[4*i+2]; o.w = v[4*i+3];
        w4[i] = o;
    }
}

extern "C" void kernel_launch(void* const* d_in, const int* in_sizes, int n_in,
                              void* d_out, int out_size, void* d_ws, size_t ws_size,
                              hipStream_t stream) {
    const float* node_attr  = (const float*)d_in[0];
    const float* edge_attr  = (const float*)d_in[1];
    const float* edge_sh    = (const float*)d_in[2];
    const float* fc_w1      = (const float*)d_in[3];
    const float* fc_b1      = (const float*)d_in[4];
    const float* fc_w2      = (const float*)d_in[5];
    const float* fc_b2      = (const float*)d_in[6];
    const float* mean_shift = (const float*)d_in[7];
    const float* aw         = (const float*)d_in[8];
    const float* ab         = (const float*)d_in[9];
    const int*   edge_index = (const int*)d_in[10];
    float* out = (float*)d_out;

    short* w1f = (short*)((char*)d_ws + W1F_OFF);
    short* w2f = (short*)((char*)d_ws + W2F_OFF);
    float* cnt = (float*)((char*)d_ws + CNT_OFF);

    (void)hipMemsetAsync(d_out, 0, (size_t)N_NODES * 80 * sizeof(float), stream);

    prep_kernel<<<(2048 + 40960 + 255) / 256, 256, 0, stream>>>(fc_w1, fc_w2, w1f, w2f, cnt);
    edge_kernel<<<EBLK, 128, 0, stream>>>(node_attr, edge_attr, edge_sh,
                                          fc_b1, fc_b2, edge_index,
                                          w1f, w2f, out, cnt);
    node_kernel<<<(N_NODES + 255) / 256, 256, 0, stream>>>(node_attr, mean_shift,
                                                           aw, ab, cnt, out);
}

// Round 3
// 343.494 us; speedup vs baseline: 1.1776x; 1.1776x over previous
//
#include <hip/hip_runtime.h>

typedef __attribute__((ext_vector_type(8))) short short8;
typedef __attribute__((ext_vector_type(4))) short bfx4;
typedef __attribute__((ext_vector_type(4))) float floatx4;

#define N_NODES 20000
#define N_EDGES 160000
#define TILE_E 64
#define EBLK (N_EDGES / TILE_E)   // 2500

#define C0f   0.14433756729740643f   // sqrt(1/48)
#define C1f   0.21650635094610965f   // sqrt(3/64)
#define IS3   0.5773502691896258f    // 1/sqrt(3)
#define IS6   0.4082482904638631f    // 1/sqrt(6)
#define EPS_LN 1e-5f

// ws layout (bytes):
//   [0, 32768)        w1f: W1 bf16, MFMA B-frag order
//   [32768, 688128)   w2f: W2 bf16, MFMA B-frag order
//   [688128, 768128)  cnt: N_NODES floats (zeroed by prep)
#define W1F_OFF 0
#define W2F_OFF 32768
#define CNT_OFF 688128

__device__ __forceinline__ short f2bf(float f) {   // fp32 -> bf16 RNE
    unsigned u = __float_as_uint(f);
    u += 0x7fff + ((u >> 16) & 1);
    return (short)(u >> 16);
}
__device__ __forceinline__ float bf2f(short s) {
    return __uint_as_float(((unsigned)(unsigned short)s) << 16);
}

__device__ __forceinline__ short8 load8_bf16(const float* p) {
    const float4* q = (const float4*)p;
    float4 f0 = q[0], f1 = q[1];
    short8 s;
    s[0]=f2bf(f0.x); s[1]=f2bf(f0.y); s[2]=f2bf(f0.z); s[3]=f2bf(f0.w);
    s[4]=f2bf(f1.x); s[5]=f2bf(f1.y); s[6]=f2bf(f1.z); s[7]=f2bf(f1.w);
    return s;
}

__device__ __forceinline__ floatx4 mfma4(const short8* a, short8 b0, short8 b1,
                                         short8 b2, short8 b3, float bias) {
    floatx4 C = {bias, bias, bias, bias};   // bias as C-init: free bias add
    C = __builtin_amdgcn_mfma_f32_16x16x32_bf16(a[0], b0, C, 0, 0, 0);
    C = __builtin_amdgcn_mfma_f32_16x16x32_bf16(a[1], b1, C, 0, 0, 0);
    C = __builtin_amdgcn_mfma_f32_16x16x32_bf16(a[2], b2, C, 0, 0, 0);
    C = __builtin_amdgcn_mfma_f32_16x16x32_bf16(a[3], b3, C, 0, 0, 0);
    return C;
}

// x-tile LDS swizzle: 4-short granules, granule g' = g ^ (row & 15).
__device__ __forceinline__ int xsw(int row, int e) {
    return row * 64 + ((e & 3) | ((((e >> 2) ^ row) & 15) << 2));
}
__device__ __forceinline__ bfx4 ldx(const short* base, int row, int gran) {
    return *(const bfx4*)(base + row * 64 + (((gran ^ row) & 15) << 2));
}

// 8 B-fragments = one pipeline group (two 16-col tiles, or one tile's F+G pair)
struct Frag8 { short8 v[8]; };

__device__ __forceinline__ void ld8(Frag8& f, const short* bp) {
    #pragma unroll
    for (int i = 0; i < 8; ++i) f.v[i] = *(const short8*)(bp + i * 512);
}
__device__ __forceinline__ void ld44(Frag8& f, const short* bpF, const short* bpG) {
    #pragma unroll
    for (int i = 0; i < 4; ++i) f.v[i] = *(const short8*)(bpF + i * 512);
    #pragma unroll
    for (int i = 0; i < 4; ++i) f.v[4 + i] = *(const short8*)(bpG + i * 512);
}

// W1/W2 -> bf16 fragment order; also zero cnt.
__global__ __launch_bounds__(256)
void prep_kernel(const float* __restrict__ fc_w1, const float* __restrict__ fc_w2,
                 short* __restrict__ w1f, short* __restrict__ w2f,
                 float* __restrict__ cnt) {
    int g = blockIdx.x * 256 + threadIdx.x;
    if (g < N_NODES) cnt[g] = 0.0f;
    if (g < 2048) {                      // W1: t<8, kt<4
        int ln = g & 15, qd = (g >> 4) & 3, kt = (g >> 6) & 3, t = g >> 8;
        int n = t * 16 + ln, kb = kt * 32 + qd * 8;
        short8 s;
        #pragma unroll
        for (int j = 0; j < 8; ++j) s[j] = f2bf(fc_w1[(kb + j) * 128 + n]);
        *(short8*)(w1f + g * 8) = s;
        return;
    }
    int g2 = g - 2048;
    if (g2 < 40960) {                    // W2: t<160, kt<4
        int ln = g2 & 15, qd = (g2 >> 4) & 3, kt = (g2 >> 6) & 3, t = g2 >> 8;
        int n = t * 16 + ln, kb = kt * 32 + qd * 8;
        short8 s;
        #pragma unroll
        for (int j = 0; j < 8; ++j) s[j] = f2bf(fc_w2[(kb + j) * 2560 + n]);
        *(short8*)(w2f + g2 * 8) = s;
    }
}

__global__ __launch_bounds__(128, 2)
void edge_kernel(const float* __restrict__ node_attr,
                 const float* __restrict__ edge_attr,
                 const float* __restrict__ edge_sh,
                 const float* __restrict__ fc_b1,
                 const float* __restrict__ fc_b2,
                 const int*   __restrict__ edge_index,
                 const short* __restrict__ w1f,
                 const short* __restrict__ w2f,
                 float* __restrict__ accum,   // d_out, pre-zeroed
                 float* __restrict__ cnt)     // zeroed by prep
{
    // s_H overlaid with x-tiles (s_H dead after a2 frags are read): 18.9 KB.
    __shared__ __align__(16) short s_pool[64 * 136];   // 17408 B
    __shared__ float s_sh[64 * 4];
    __shared__ int   s_src[64];
    __shared__ int   s_dst[64];

    short* s_H    = s_pool;            // [64][136] bf16 hidden activations
    short* s_x0t  = s_pool;            // [32][64] swizzled: [u][e']
    short* s_x1t  = s_pool + 2048;     // [48][64] swizzled: [u*3+i][e']
    short* s_x1dt = s_pool + 5120;     // [16][64] swizzled: [u][e']

    const int tid = threadIdx.x;
    const int e0  = blockIdx.x * TILE_E;

    // ---- phase A: indices, sh ----
    if (tid < 64) {
        int s = edge_index[e0 + tid];
        int d = edge_index[N_EDGES + e0 + tid];
        s_src[tid] = s; s_dst[tid] = d;
        atomicAdd(&cnt[s], 1.0f);
    }
    s_sh[tid]       = edge_sh[(size_t)e0 * 4 + tid];
    s_sh[tid + 128] = edge_sh[(size_t)e0 * 4 + tid + 128];
    __syncthreads();

    // ---- per-wave identity: wave owns 32 edges as 2 MFMA groups ----
    const int lane = tid & 63;
    const int wv   = tid >> 6;
    const int ln   = lane & 15;
    const int qd   = lane >> 4;
    const int eb0  = wv * 32 + qd * 4;        // group 0 C-row base
    const int eb1  = eb0 + 16;                // group 1
    const int gr0  = eb0 >> 2;                // swizzle granules
    const int gr1  = eb1 >> 2;

    // ---- MLP1: h = relu(EA @ W1 + b1) via MFMA ----
    {
        short8 a1[2][4];
        #pragma unroll
        for (int g = 0; g < 2; ++g) {
            const float* ap = edge_attr + (size_t)(e0 + wv*32 + g*16 + ln) * 128 + qd * 8;
            #pragma unroll
            for (int kt = 0; kt < 4; ++kt) a1[g][kt] = load8_bf16(ap + kt * 32);
        }
        #pragma unroll
        for (int t = 0; t < 8; ++t) {
            const short* bp = w1f + t * 2048 + lane * 8;
            short8 b0 = *(const short8*)bp;
            short8 b1 = *(const short8*)(bp + 512);
            short8 b2 = *(const short8*)(bp + 1024);
            short8 b3 = *(const short8*)(bp + 1536);
            float bias = fc_b1[t * 16 + ln];
            #pragma unroll
            for (int g = 0; g < 2; ++g) {
                floatx4 C = mfma4(a1[g], b0, b1, b2, b3, bias);
                #pragma unroll
                for (int r = 0; r < 4; ++r)
                    s_H[(wv*32 + g*16 + qd*4 + r) * 136 + t*16 + ln] = f2bf(fmaxf(C[r], 0.f));
            }
        }
    }

    // A2 fragments — wave-private s_H rows; compiler's lgkmcnt handles RAW.
    short8 a2[2][4];
    #pragma unroll
    for (int g = 0; g < 2; ++g) {
        const short* hp = s_H + (wv*32 + g*16 + ln) * 136 + qd * 8;
        #pragma unroll
        for (int kt = 0; kt < 4; ++kt) a2[g][kt] = *(const short8*)(hp + kt * 32);
    }
    __syncthreads();   // ALL waves done reading s_H before x-tiles overwrite it

    // ---- gather (transposed, swizzled bf16) + x1.sh1 dot ----
    #pragma unroll
    for (int i = 0; i < 40; ++i) {
        int f = tid + i * 128;
        int e = f / 80, c = f % 80;
        float v = node_attr[(size_t)s_dst[e] * 80 + c];
        if (c < 32) s_x0t[xsw(c, e)] = f2bf(v);
        else        s_x1t[xsw(c - 32, e)] = f2bf(v);
    }
    #pragma unroll
    for (int i = 0; i < 8; ++i) {
        int it = tid + i * 128;
        int e = it >> 4, u = it & 15;
        const float* xp = node_attr + (size_t)s_dst[e] * 80 + 32 + u * 3;
        float d = xp[0] * s_sh[e*4+1] + xp[1] * s_sh[e*4+2] + xp[2] * s_sh[e*4+3];
        s_x1dt[xsw(u, e)] = f2bf(d);
    }
    __syncthreads();

    const short* wbase = w2f + lane * 8;

    // ======== main loop: manual depth-1 register ping-pong (fA/fB) ========
    // Each group = 8 coalesced 16B loads issued one group AHEAD of its MFMAs,
    // so the ~200cyc L2 latency hides under the previous group's compute.

    // ---- PHASE 1: out0 (regions 1-2) ----
    float r0lo[2][4] = {}, r0hi[2][4] = {}, r1lo[2][4] = {}, r1hi[2][4] = {};

    {   // region 1: groups u=0..31, tiles 2u,2u+1
        auto consume1 = [&](const Frag8& f, int u, float blo, float bhi) {
            #pragma unroll
            for (int g = 0; g < 2; ++g) {
                floatx4 Clo = mfma4(a2[g], f.v[0], f.v[1], f.v[2], f.v[3], blo);
                floatx4 Chi = mfma4(a2[g], f.v[4], f.v[5], f.v[6], f.v[7], bhi);
                bfx4 xs = ldx(s_x0t, u, g ? gr1 : gr0);
                #pragma unroll
                for (int r = 0; r < 4; ++r) {
                    float a = bf2f(xs[r]);
                    r0lo[g][r] += a * Clo[r];
                    r0hi[g][r] += a * Chi[r];
                }
            }
        };
        Frag8 fA, fB;
        ld8(fA, wbase);
        #pragma unroll 1
        for (int u = 0; u < 32; u += 2) {
            float bloA = fc_b2[2*u*16 + ln],       bhiA = fc_b2[2*u*16 + 16 + ln];
            float bloB = fc_b2[(2*u+2)*16 + ln],   bhiB = fc_b2[(2*u+2)*16 + 16 + ln];
            ld8(fB, wbase + (size_t)(2*u + 2) * 2048);
            consume1(fA, u, bloA, bhiA);
            if (u + 2 < 32) ld8(fA, wbase + (size_t)(2*u + 4) * 2048);
            consume1(fB, u + 1, bloB, bhiB);
        }
    }
    {   // region 2: groups u=0..15, tiles 64+2u,65+2u
        auto consume2 = [&](const Frag8& f, int u, float blo, float bhi) {
            #pragma unroll
            for (int g = 0; g < 2; ++g) {
                floatx4 Clo = mfma4(a2[g], f.v[0], f.v[1], f.v[2], f.v[3], blo);
                floatx4 Chi = mfma4(a2[g], f.v[4], f.v[5], f.v[6], f.v[7], bhi);
                bfx4 xs = ldx(s_x1dt, u, g ? gr1 : gr0);
                #pragma unroll
                for (int r = 0; r < 4; ++r) {
                    float a = bf2f(xs[r]);
                    r1lo[g][r] += a * Clo[r];
                    r1hi[g][r] += a * Chi[r];
                }
            }
        };
        Frag8 fA, fB;
        ld8(fA, wbase + (size_t)64 * 2048);
        #pragma unroll 1
        for (int u = 0; u < 16; u += 2) {
            float bloA = fc_b2[(64 + 2*u)*16 + ln], bhiA = fc_b2[(64 + 2*u)*16 + 16 + ln];
            float bloB = fc_b2[(66 + 2*u)*16 + ln], bhiB = fc_b2[(66 + 2*u)*16 + 16 + ln];
            ld8(fB, wbase + (size_t)(66 + 2*u) * 2048);
            consume2(fA, u, bloA, bhiA);
            if (u + 2 < 16) ld8(fA, wbase + (size_t)(68 + 2*u) * 2048);
            consume2(fB, u + 1, bloB, bhiB);
        }
    }
    // phase-1 epilogue: out0 scatter
    #pragma unroll
    for (int g = 0; g < 2; ++g)
        #pragma unroll
        for (int r = 0; r < 4; ++r) {
            int e = (g ? eb1 : eb0) + r;
            float sh0 = s_sh[e*4];
            int base = s_src[e] * 80;
            atomicAdd(&accum[base + ln],      C0f * (sh0 * r0lo[g][r] + IS3 * r1lo[g][r]));
            atomicAdd(&accum[base + 16 + ln], C0f * (sh0 * r0hi[g][r] + IS3 * r1hi[g][r]));
        }

    // ---- PHASE 2: out1 (regions 3-5) ----
    float r3[2][4] = {};
    float r4[2][4][3] = {};
    float r5[2][4][3] = {};

    {   // region 3: 16 groups, each covers tiles 96+2c, 97+2c (u=2c, 2c+1)
        auto consume3 = [&](const short8* fr, int u, float bias) {
            #pragma unroll
            for (int g = 0; g < 2; ++g) {
                floatx4 C = mfma4(a2[g], fr[0], fr[1], fr[2], fr[3], bias);
                bfx4 xs = ldx(s_x0t, u, g ? gr1 : gr0);
                #pragma unroll
                for (int r = 0; r < 4; ++r)
                    r3[g][r] += bf2f(xs[r]) * C[r];
            }
        };
        Frag8 fA, fB;
        ld8(fA, wbase + (size_t)96 * 2048);
        #pragma unroll 1
        for (int c = 0; c < 16; c += 2) {
            float b0A = fc_b2[(96 + 2*c)*16 + ln], b1A = fc_b2[(97 + 2*c)*16 + ln];
            float b0B = fc_b2[(98 + 2*c)*16 + ln], b1B = fc_b2[(99 + 2*c)*16 + ln];
            ld8(fB, wbase + (size_t)(98 + 2*c) * 2048);
            consume3(&fA.v[0], 2*c,     b0A);
            consume3(&fA.v[4], 2*c + 1, b1A);
            if (c + 2 < 16) ld8(fA, wbase + (size_t)(100 + 2*c) * 2048);
            consume3(&fB.v[0], 2*c + 2, b0B);
            consume3(&fB.v[4], 2*c + 3, b1B);
        }
    }
    {   // regions 4+5: groups u=0..15, tiles 128+u (F) and 144+u (G)
        auto consume45 = [&](const Frag8& f, int u, float b4, float b5) {
            #pragma unroll
            for (int g = 0; g < 2; ++g) {
                floatx4 C4 = mfma4(a2[g], f.v[0], f.v[1], f.v[2], f.v[3], b4);
                floatx4 C5 = mfma4(a2[g], f.v[4], f.v[5], f.v[6], f.v[7], b5);
                int gr = (g ? gr1 : gr0);
                bfx4 x0s = ldx(s_x1t, u*3 + 0, gr);
                bfx4 x1s = ldx(s_x1t, u*3 + 1, gr);
                bfx4 x2s = ldx(s_x1t, u*3 + 2, gr);
                #pragma unroll
                for (int r = 0; r < 4; ++r) {
                    float a0 = bf2f(x0s[r]), a1 = bf2f(x1s[r]), a2v = bf2f(x2s[r]);
                    r4[g][r][0] += a0 * C4[r];  r5[g][r][0] += a0 * C5[r];
                    r4[g][r][1] += a1 * C4[r];  r5[g][r][1] += a1 * C5[r];
                    r4[g][r][2] += a2v * C4[r]; r5[g][r][2] += a2v * C5[r];
                }
            }
        };
        Frag8 fA, fB;
        ld44(fA, wbase + (size_t)128 * 2048, wbase + (size_t)144 * 2048);
        #pragma unroll 1
        for (int u = 0; u < 16; u += 2) {
            float b4A = fc_b2[(128 + u)*16 + ln], b5A = fc_b2[(144 + u)*16 + ln];
            float b4B = fc_b2[(129 + u)*16 + ln], b5B = fc_b2[(145 + u)*16 + ln];
            ld44(fB, wbase + (size_t)(129 + u) * 2048, wbase + (size_t)(145 + u) * 2048);
            consume45(fA, u, b4A, b5A);
            if (u + 2 < 16)
                ld44(fA, wbase + (size_t)(130 + u) * 2048, wbase + (size_t)(146 + u) * 2048);
            consume45(fB, u + 1, b4B, b5B);
        }
    }
    // phase-2 epilogue: out1 scatter
    #pragma unroll
    for (int g = 0; g < 2; ++g)
        #pragma unroll
        for (int r = 0; r < 4; ++r) {
            int e = (g ? eb1 : eb0) + r;
            float sh0 = s_sh[e*4], sa = s_sh[e*4+1], sb = s_sh[e*4+2], sc = s_sh[e*4+3];
            int base = s_src[e] * 80;
            float t3 = C1f * IS3 * r3[g][r];
            float s0 = C1f * IS3 * sh0;
            float c6 = C1f * IS6;
            float v50 = r5[g][r][1] * sc - r5[g][r][2] * sb;
            float v51 = r5[g][r][2] * sa - r5[g][r][0] * sc;
            float v52 = r5[g][r][0] * sb - r5[g][r][1] * sa;
            atomicAdd(&accum[base + 32 + ln*3 + 0], sa * t3 + s0 * r4[g][r][0] + c6 * v50);
            atomicAdd(&accum[base + 32 + ln*3 + 1], sb * t3 + s0 * r4[g][r][1] + c6 * v51);
            atomicAdd(&accum[base + 32 + ln*3 + 2], sc * t3 + s0 * r4[g][r][2] + c6 * v52);
        }
}

// Per-node: mean-divide, residual, equivariant layernorm. In-place on d_out.
__global__ __launch_bounds__(256)
void node_kernel(const float* __restrict__ node_attr,
                 const float* __restrict__ mean_shift,
                 const float* __restrict__ aw,
                 const float* __restrict__ ab,
                 const float* __restrict__ cnt,
                 float* __restrict__ out)
{
    int n = blockIdx.x * blockDim.x + threadIdx.x;
    if (n >= N_NODES) return;
    float inv = 1.0f / fmaxf(cnt[n], 1.0f);
    size_t base = (size_t)n * 80;
    float v[80];
    const float4* o4 = (const float4*)(out + base);
    const float4* a4 = (const float4*)(node_attr + base);
    #pragma unroll
    for (int i = 0; i < 20; ++i) {
        float4 o = o4[i], a = a4[i];
        v[4*i+0] = o.x * inv + a.x;
        v[4*i+1] = o.y * inv + a.y;
        v[4*i+2] = o.z * inv + a.z;
        v[4*i+3] = o.w * inv + a.w;
    }

    float m0 = 0.f;
    #pragma unroll
    for (int u = 0; u < 32; ++u) m0 += v[u];
    m0 *= (1.0f / 32.0f);
    float n0 = 0.f;
    #pragma unroll
    for (int u = 0; u < 32; ++u) {
        float f = v[u] - m0 * mean_shift[u];
        v[u] = f;
        n0 += f * f;
    }
    n0 = rsqrtf(n0 * (1.0f / 32.0f) + EPS_LN);
    #pragma unroll
    for (int u = 0; u < 32; ++u) v[u] = v[u] * (n0 * aw[u]) + ab[u];

    float m1[3] = {0.f, 0.f, 0.f};
    #pragma unroll
    for (int u = 0; u < 16; ++u)
        #pragma unroll
        for (int i = 0; i < 3; ++i) m1[i] += v[32 + u*3 + i];
    #pragma unroll
    for (int i = 0; i < 3; ++i) m1[i] *= (1.0f / 16.0f);
    float n1 = 0.f;
    #pragma unroll
    for (int u = 0; u < 16; ++u)
        #pragma unroll
        for (int i = 0; i < 3; ++i) {
            float f = v[32 + u*3 + i] - m1[i] * mean_shift[32 + u];
            v[32 + u*3 + i] = f;
            n1 += f * f;
        }
    n1 = rsqrtf(n1 * (1.0f / 48.0f) + EPS_LN);
    #pragma unroll
    for (int u = 0; u < 16; ++u)
        #pragma unroll
        for (int i = 0; i < 3; ++i)
            v[32 + u*3 + i] *= (n1 * aw[32 + u]);

    float4* w4 = (float4*)(out + base);
    #pragma unroll
    for (int i = 0; i < 20; ++i) {
        float4 o; o.x = v[4*i]; o.y = v[4*i+1]; o.z = v[4*i+2]; o.w = v[4*i+3];
        w4[i] = o;
    }
}

extern "C" void kernel_launch(void* const* d_in, const int* in_sizes, int n_in,
                              void* d_out, int out_size, void* d_ws, size_t ws_size,
                              hipStream_t stream) {
    const float* node_attr  = (const float*)d_in[0];
    const float* edge_attr  = (const float*)d_in[1];
    const float* edge_sh    = (const float*)d_in[2];
    const float* fc_w1      = (const float*)d_in[3];
    const float* fc_b1      = (const float*)d_in[4];
    const float* fc_w2      = (const float*)d_in[5];
    const float* fc_b2      = (const float*)d_in[6];
    const float* mean_shift = (const float*)d_in[7];
    const float* aw         = (const float*)d_in[8];
    const float* ab         = (const float*)d_in[9];
    const int*   edge_index = (const int*)d_in[10];
    float* out = (float*)d_out;

    short* w1f = (short*)((char*)d_ws + W1F_OFF);
    short* w2f = (short*)((char*)d_ws + W2F_OFF);
    float* cnt = (float*)((char*)d_ws + CNT_OFF);

    (void)hipMemsetAsync(d_out, 0, (size_t)N_NODES * 80 * sizeof(float), stream);

    prep_kernel<<<(2048 + 40960 + 255) / 256, 256, 0, stream>>>(fc_w1, fc_w2, w1f, w2f, cnt);
    edge_kernel<<<EBLK, 128, 0, stream>>>(node_attr, edge_attr, edge_sh,
                                          fc_b1, fc_b2, edge_index,
                                          w1f, w2f, out, cnt);
    node_kernel<<<(N_NODES + 255) / 256, 256, 0, stream>>>(node_attr, mean_shift,
                                                           aw, ab, cnt, out);
}

// Round 4
// 336.367 us; speedup vs baseline: 1.2025x; 1.0212x over previous
//
#include <hip/hip_runtime.h>

typedef __attribute__((ext_vector_type(8))) short short8;
typedef __attribute__((ext_vector_type(4))) short bfx4;
typedef __attribute__((ext_vector_type(4))) float floatx4;

#define N_NODES 20000
#define N_EDGES 160000
#define TILE_E 128
#define EBLK (N_EDGES / TILE_E)   // 1250

#define C0f   0.14433756729740643f   // sqrt(1/48)
#define C1f   0.21650635094610965f   // sqrt(3/64)
#define IS3   0.5773502691896258f    // 1/sqrt(3)
#define IS6   0.4082482904638631f    // 1/sqrt(6)
#define EPS_LN 1e-5f

// ws layout (bytes):
//   [0, 32768)        w1f: W1 bf16, MFMA B-frag order
//   [32768, 688128)   w2f: W2 bf16, MFMA B-frag order, LINEAR STREAM ORDER
//                     (regions 4/5 interleaved: pos 128+2u <- tile 128+u,
//                      pos 129+2u <- tile 144+u)
//   [688128, 768128)  cnt: N_NODES floats (zeroed by prep)
#define W1F_OFF 0
#define W2F_OFF 32768
#define CNT_OFF 688128

__device__ __forceinline__ short f2bf(float f) {   // fp32 -> bf16 RNE
    unsigned u = __float_as_uint(f);
    u += 0x7fff + ((u >> 16) & 1);
    return (short)(u >> 16);
}
__device__ __forceinline__ float bf2f(short s) {
    return __uint_as_float(((unsigned)(unsigned short)s) << 16);
}

__device__ __forceinline__ short8 load8_bf16(const float* p) {
    const float4* q = (const float4*)p;
    float4 f0 = q[0], f1 = q[1];
    short8 s;
    s[0]=f2bf(f0.x); s[1]=f2bf(f0.y); s[2]=f2bf(f0.z); s[3]=f2bf(f0.w);
    s[4]=f2bf(f1.x); s[5]=f2bf(f1.y); s[6]=f2bf(f1.z); s[7]=f2bf(f1.w);
    return s;
}

__device__ __forceinline__ floatx4 mfma4(const short8* a, short8 b0, short8 b1,
                                         short8 b2, short8 b3, float bias) {
    floatx4 C = {bias, bias, bias, bias};   // bias as C-init: free bias add
    C = __builtin_amdgcn_mfma_f32_16x16x32_bf16(a[0], b0, C, 0, 0, 0);
    C = __builtin_amdgcn_mfma_f32_16x16x32_bf16(a[1], b1, C, 0, 0, 0);
    C = __builtin_amdgcn_mfma_f32_16x16x32_bf16(a[2], b2, C, 0, 0, 0);
    C = __builtin_amdgcn_mfma_f32_16x16x32_bf16(a[3], b3, C, 0, 0, 0);
    return C;
}

// x-tile LDS swizzle within a 64-edge half: 4-short granules, g' = g ^ (row&15)
__device__ __forceinline__ int xsw(int row, int el) {
    return row * 64 + ((el & 3) | ((((el >> 2) ^ row) & 15) << 2));
}
__device__ __forceinline__ bfx4 ldx(const short* base, int row, int gran) {
    return *(const bfx4*)(base + row * 64 + (((gran ^ row) & 15) << 2));
}

// W1/W2 -> bf16 fragment order (W2 in linear stream order); also zero cnt.
__global__ __launch_bounds__(256)
void prep_kernel(const float* __restrict__ fc_w1, const float* __restrict__ fc_w2,
                 short* __restrict__ w1f, short* __restrict__ w2f,
                 float* __restrict__ cnt) {
    int g = blockIdx.x * 256 + threadIdx.x;
    if (g < N_NODES) cnt[g] = 0.0f;
    if (g < 2048) {                      // W1: t<8, kt<4
        int ln = g & 15, qd = (g >> 4) & 3, kt = (g >> 6) & 3, t = g >> 8;
        int n = t * 16 + ln, kb = kt * 32 + qd * 8;
        short8 s;
        #pragma unroll
        for (int j = 0; j < 8; ++j) s[j] = f2bf(fc_w1[(kb + j) * 128 + n]);
        *(short8*)(w1f + g * 8) = s;
        return;
    }
    int g2 = g - 2048;
    if (g2 < 40960) {                    // W2: t<160, kt<4
        int ln = g2 & 15, qd = (g2 >> 4) & 3, kt = (g2 >> 6) & 3, t = g2 >> 8;
        int n = t * 16 + ln, kb = kt * 32 + qd * 8;
        short8 s;
        #pragma unroll
        for (int j = 0; j < 8; ++j) s[j] = f2bf(fc_w2[(kb + j) * 2560 + n]);
        // linear-stream reorder: interleave regions 4/5
        int p = (t < 128) ? t : (t < 144 ? 128 + 2 * (t - 128) : 129 + 2 * (t - 144));
        *(short8*)(w2f + (size_t)p * 2048 + (g2 & 255) * 8) = s;
    }
}

__global__ __launch_bounds__(256, 2)
void edge_kernel(const float* __restrict__ node_attr,
                 const float* __restrict__ edge_attr,
                 const float* __restrict__ edge_sh,
                 const float* __restrict__ fc_b1,
                 const float* __restrict__ fc_b2,
                 const int*   __restrict__ edge_index,
                 const short* __restrict__ w1f,
                 const short* __restrict__ w2f,
                 float* __restrict__ accum,   // d_out, pre-zeroed
                 float* __restrict__ cnt)     // zeroed by prep
{
    // s_pool: s_H (128x136) overlaid with x-tiles (dead after a2 frags read).
    __shared__ __align__(16) short s_pool[128 * 136];  // 34816 B
    __shared__ __align__(16) short s_w2[2 * 8192];     // 32768 B: 2 x 4-tile chunk
    __shared__ float s_sh[128 * 4];
    __shared__ int   s_src[128];
    __shared__ int   s_dst[128];

    short* s_H    = s_pool;             // [128][136]
    short* s_x0t  = s_pool;             // [2][32][64]  half-split, swizzled
    short* s_x1t  = s_pool + 4096;      // [2][48][64]
    short* s_x1dt = s_pool + 10240;     // [2][16][64]

    const int tid  = threadIdx.x;
    const int e0   = blockIdx.x * TILE_E;
    const int lane = tid & 63;
    const int wv   = tid >> 6;

    // Prefetch chunk 0 into regs immediately (lands during MLP1/gather).
    float4 st0, st1, st2, st3;
    {
        const float4* sp = (const float4*)w2f;
        st0 = sp[tid]; st1 = sp[tid + 256]; st2 = sp[tid + 512]; st3 = sp[tid + 768];
    }

    // ---- phase A: indices, sh ----
    if (tid < 128) {
        int s = edge_index[e0 + tid];
        int d = edge_index[N_EDGES + e0 + tid];
        s_src[tid] = s; s_dst[tid] = d;
        atomicAdd(&cnt[s], 1.0f);
    }
    s_sh[tid]       = edge_sh[(size_t)e0 * 4 + tid];
    s_sh[tid + 256] = edge_sh[(size_t)e0 * 4 + tid + 256];
    __syncthreads();

    // ---- per-wave identity: wave owns 32 edges (2 MFMA groups) ----
    const int ln   = lane & 15;
    const int qd   = lane >> 4;
    const int eb0  = wv * 32 + qd * 4;        // block-local edge base, group 0
    const int eb1  = eb0 + 16;                // group 1
    const int half = wv >> 1;                 // which 64-edge half
    const int gr0  = (wv & 1) * 8 + qd;       // swizzle granule within half
    const int gr1  = gr0 + 4;
    const short* x0b  = s_x0t  + half * 2048;
    const short* x1b  = s_x1t  + half * 3072;
    const short* x1db = s_x1dt + half * 1024;

    // ---- MLP1: h = relu(EA @ W1 + b1) via MFMA ----
    {
        short8 a1[2][4];
        #pragma unroll
        for (int g = 0; g < 2; ++g) {
            const float* ap = edge_attr + (size_t)(e0 + wv*32 + g*16 + ln) * 128 + qd * 8;
            #pragma unroll
            for (int kt = 0; kt < 4; ++kt) a1[g][kt] = load8_bf16(ap + kt * 32);
        }
        #pragma unroll
        for (int t = 0; t < 8; ++t) {
            const short* bp = w1f + t * 2048 + lane * 8;
            short8 b0 = *(const short8*)bp;
            short8 b1 = *(const short8*)(bp + 512);
            short8 b2 = *(const short8*)(bp + 1024);
            short8 b3 = *(const short8*)(bp + 1536);
            float bias = fc_b1[t * 16 + ln];
            #pragma unroll
            for (int g = 0; g < 2; ++g) {
                floatx4 C = mfma4(a1[g], b0, b1, b2, b3, bias);
                #pragma unroll
                for (int r = 0; r < 4; ++r)
                    s_H[(wv*32 + g*16 + qd*4 + r) * 136 + t*16 + ln] = f2bf(fmaxf(C[r], 0.f));
            }
        }
    }

    // A2 fragments — wave-private s_H rows; compiler's lgkmcnt handles RAW.
    short8 a2[2][4];
    #pragma unroll
    for (int g = 0; g < 2; ++g) {
        const short* hp = s_H + (wv*32 + g*16 + ln) * 136 + qd * 8;
        #pragma unroll
        for (int kt = 0; kt < 4; ++kt) a2[g][kt] = *(const short8*)(hp + kt * 32);
    }
    __syncthreads();   // ALL waves done reading s_H before x-tiles overwrite it

    // ---- gather (transposed, swizzled bf16, half-split) + x1.sh1 dot ----
    #pragma unroll
    for (int i = 0; i < 40; ++i) {
        int f = tid + i * 256;
        int e = f / 80, c = f % 80;
        float v = node_attr[(size_t)s_dst[e] * 80 + c];
        int hf = e >> 6, el = e & 63;
        if (c < 32) s_x0t[hf * 2048 + xsw(c, el)] = f2bf(v);
        else        s_x1t[hf * 3072 + xsw(c - 32, el)] = f2bf(v);
    }
    #pragma unroll
    for (int i = 0; i < 8; ++i) {
        int it = tid + i * 256;
        int e = it >> 4, u = it & 15;
        const float* xp = node_attr + (size_t)s_dst[e] * 80 + 32 + u * 3;
        float d = xp[0] * s_sh[e*4+1] + xp[1] * s_sh[e*4+2] + xp[2] * s_sh[e*4+3];
        s_x1dt[(e >> 6) * 1024 + xsw(u, e & 63)] = f2bf(d);
    }
    __syncthreads();

    // ---- staging prologue: WRITE(0); LOAD(1); barrier ----
    {
        float4* dp = (float4*)s_w2;
        dp[tid] = st0; dp[tid+256] = st1; dp[tid+512] = st2; dp[tid+768] = st3;
        const float4* sp = (const float4*)(w2f + (size_t)8192);
        st0 = sp[tid]; st1 = sp[tid+256]; st2 = sp[tid+512]; st3 = sp[tid+768];
    }
    __syncthreads();

    // ======== W2 stream: 40 chunks x 4 tiles, LDS double-buffered ========
    // Per chunk c: ds_write chunk c+1 (regs from last iter), global-load
    // chunk c+2 -> regs, consume chunk c from LDS, __syncthreads.
    // The barrier's vmcnt drain is covered: each load has a full chunk of
    // compute (~400cyc) in flight before anything waits on it.

    // ---- PHASE 1: out0 ----
    float r0lo[2][4] = {}, r0hi[2][4] = {}, r1lo[2][4] = {}, r1hi[2][4] = {};

    #pragma unroll 1
    for (int c = 0; c < 16; ++c) {       // region 1: chunks 0..15 (u = 2c, 2c+1)
        {
            float4* dp = (float4*)(s_w2 + ((c + 1) & 1) * 8192);
            dp[tid] = st0; dp[tid+256] = st1; dp[tid+512] = st2; dp[tid+768] = st3;
            const float4* sp = (const float4*)(w2f + (size_t)(c + 2) * 8192);
            st0 = sp[tid]; st1 = sp[tid+256]; st2 = sp[tid+512]; st3 = sp[tid+768];
        }
        const short* bb = s_w2 + (c & 1) * 8192 + lane * 8;
        #pragma unroll
        for (int t = 0; t < 2; ++t) {
            const int u = 2 * c + t;
            const short* bp = bb + t * 4096;
            short8 L0 = *(const short8*)bp,          L1 = *(const short8*)(bp + 512);
            short8 L2 = *(const short8*)(bp + 1024), L3 = *(const short8*)(bp + 1536);
            short8 H0 = *(const short8*)(bp + 2048), H1 = *(const short8*)(bp + 2560);
            short8 H2 = *(const short8*)(bp + 3072), H3 = *(const short8*)(bp + 3584);
            float blo = fc_b2[u * 32 + ln], bhi = fc_b2[u * 32 + 16 + ln];
            #pragma unroll
            for (int g = 0; g < 2; ++g) {
                floatx4 Clo = mfma4(a2[g], L0, L1, L2, L3, blo);
                floatx4 Chi = mfma4(a2[g], H0, H1, H2, H3, bhi);
                bfx4 xs = ldx(x0b, u, g ? gr1 : gr0);
                #pragma unroll
                for (int r = 0; r < 4; ++r) {
                    float a = bf2f(xs[r]);
                    r0lo[g][r] += a * Clo[r];
                    r0hi[g][r] += a * Chi[r];
                }
            }
        }
        __syncthreads();
    }
    #pragma unroll 1
    for (int c2 = 0; c2 < 8; ++c2) {     // region 2: chunks 16..23 (u = 2c2, 2c2+1)
        const int c = 16 + c2;
        {
            float4* dp = (float4*)(s_w2 + ((c + 1) & 1) * 8192);
            dp[tid] = st0; dp[tid+256] = st1; dp[tid+512] = st2; dp[tid+768] = st3;
            const float4* sp = (const float4*)(w2f + (size_t)(c + 2) * 8192);
            st0 = sp[tid]; st1 = sp[tid+256]; st2 = sp[tid+512]; st3 = sp[tid+768];
        }
        const short* bb = s_w2 + (c & 1) * 8192 + lane * 8;
        #pragma unroll
        for (int t = 0; t < 2; ++t) {
            const int u = 2 * c2 + t;
            const short* bp = bb + t * 4096;
            short8 L0 = *(const short8*)bp,          L1 = *(const short8*)(bp + 512);
            short8 L2 = *(const short8*)(bp + 1024), L3 = *(const short8*)(bp + 1536);
            short8 H0 = *(const short8*)(bp + 2048), H1 = *(const short8*)(bp + 2560);
            short8 H2 = *(const short8*)(bp + 3072), H3 = *(const short8*)(bp + 3584);
            float blo = fc_b2[1024 + u * 32 + ln], bhi = fc_b2[1024 + u * 32 + 16 + ln];
            #pragma unroll
            for (int g = 0; g < 2; ++g) {
                floatx4 Clo = mfma4(a2[g], L0, L1, L2, L3, blo);
                floatx4 Chi = mfma4(a2[g], H0, H1, H2, H3, bhi);
                bfx4 xs = ldx(x1db, u, g ? gr1 : gr0);
                #pragma unroll
                for (int r = 0; r < 4; ++r) {
                    float a = bf2f(xs[r]);
                    r1lo[g][r] += a * Clo[r];
                    r1hi[g][r] += a * Chi[r];
                }
            }
        }
        __syncthreads();
    }
    // phase-1 epilogue: out0 scatter
    #pragma unroll
    for (int g = 0; g < 2; ++g)
        #pragma unroll
        for (int r = 0; r < 4; ++r) {
            int e = (g ? eb1 : eb0) + r;
            float sh0 = s_sh[e*4];
            int base = s_src[e] * 80;
            atomicAdd(&accum[base + ln],      C0f * (sh0 * r0lo[g][r] + IS3 * r1lo[g][r]));
            atomicAdd(&accum[base + 16 + ln], C0f * (sh0 * r0hi[g][r] + IS3 * r1hi[g][r]));
        }

    // ---- PHASE 2: out1 ----
    float r3[2][4] = {};
    float r4[2][4][3] = {};
    float r5[2][4][3] = {};

    #pragma unroll 1
    for (int c3 = 0; c3 < 8; ++c3) {     // region 3: chunks 24..31 (u = 4c3..4c3+3)
        const int c = 24 + c3;
        {
            float4* dp = (float4*)(s_w2 + ((c + 1) & 1) * 8192);
            dp[tid] = st0; dp[tid+256] = st1; dp[tid+512] = st2; dp[tid+768] = st3;
            const float4* sp = (const float4*)(w2f + (size_t)(c + 2) * 8192);
            st0 = sp[tid]; st1 = sp[tid+256]; st2 = sp[tid+512]; st3 = sp[tid+768];
        }
        const short* bb = s_w2 + (c & 1) * 8192 + lane * 8;
        #pragma unroll
        for (int t = 0; t < 4; ++t) {
            const int u = 4 * c3 + t;
            const short* bp = bb + t * 2048;
            short8 b0 = *(const short8*)bp,          b1 = *(const short8*)(bp + 512);
            short8 b2 = *(const short8*)(bp + 1024), b3 = *(const short8*)(bp + 1536);
            float bias = fc_b2[1536 + u * 16 + ln];
            #pragma unroll
            for (int g = 0; g < 2; ++g) {
                floatx4 C = mfma4(a2[g], b0, b1, b2, b3, bias);
                bfx4 xs = ldx(x0b, u, g ? gr1 : gr0);
                #pragma unroll
                for (int r = 0; r < 4; ++r)
                    r3[g][r] += bf2f(xs[r]) * C[r];
            }
        }
        __syncthreads();
    }
    #pragma unroll 1
    for (int c4 = 0; c4 < 8; ++c4) {     // regions 4+5: chunks 32..39 (FGFG)
        const int c = 32 + c4;
        if (c4 < 7) {
            float4* dp = (float4*)(s_w2 + ((c + 1) & 1) * 8192);
            dp[tid] = st0; dp[tid+256] = st1; dp[tid+512] = st2; dp[tid+768] = st3;
            if (c4 < 6) {
                const float4* sp = (const float4*)(w2f + (size_t)(c + 2) * 8192);
                st0 = sp[tid]; st1 = sp[tid+256]; st2 = sp[tid+512]; st3 = sp[tid+768];
            }
        }
        const short* bb = s_w2 + (c & 1) * 8192 + lane * 8;
        #pragma unroll
        for (int t = 0; t < 2; ++t) {
            const int u = 2 * c4 + t;
            const short* bpF = bb + (2 * t) * 2048;
            short8 F0 = *(const short8*)bpF,          F1 = *(const short8*)(bpF + 512);
            short8 F2 = *(const short8*)(bpF + 1024), F3 = *(const short8*)(bpF + 1536);
            short8 G0 = *(const short8*)(bpF + 2048), G1 = *(const short8*)(bpF + 2560);
            short8 G2 = *(const short8*)(bpF + 3072), G3 = *(const short8*)(bpF + 3584);
            float b4 = fc_b2[2048 + u * 16 + ln], b5 = fc_b2[2304 + u * 16 + ln];
            #pragma unroll
            for (int g = 0; g < 2; ++g) {
                floatx4 C4 = mfma4(a2[g], F0, F1, F2, F3, b4);
                floatx4 C5 = mfma4(a2[g], G0, G1, G2, G3, b5);
                int gr = (g ? gr1 : gr0);
                bfx4 x0s = ldx(x1b, u*3 + 0, gr);
                bfx4 x1s = ldx(x1b, u*3 + 1, gr);
                bfx4 x2s = ldx(x1b, u*3 + 2, gr);
                #pragma unroll
                for (int r = 0; r < 4; ++r) {
                    float a0 = bf2f(x0s[r]), a1 = bf2f(x1s[r]), a2v = bf2f(x2s[r]);
                    r4[g][r][0] += a0 * C4[r];  r5[g][r][0] += a0 * C5[r];
                    r4[g][r][1] += a1 * C4[r];  r5[g][r][1] += a1 * C5[r];
                    r4[g][r][2] += a2v * C4[r]; r5[g][r][2] += a2v * C5[r];
                }
            }
        }
        if (c4 < 7) __syncthreads();
    }
    // phase-2 epilogue: out1 scatter
    #pragma unroll
    for (int g = 0; g < 2; ++g)
        #pragma unroll
        for (int r = 0; r < 4; ++r) {
            int e = (g ? eb1 : eb0) + r;
            float sh0 = s_sh[e*4], sa = s_sh[e*4+1], sb = s_sh[e*4+2], sc = s_sh[e*4+3];
            int base = s_src[e] * 80;
            float t3 = C1f * IS3 * r3[g][r];
            float s0 = C1f * IS3 * sh0;
            float c6 = C1f * IS6;
            float v50 = r5[g][r][1] * sc - r5[g][r][2] * sb;
            float v51 = r5[g][r][2] * sa - r5[g][r][0] * sc;
            float v52 = r5[g][r][0] * sb - r5[g][r][1] * sa;
            atomicAdd(&accum[base + 32 + ln*3 + 0], sa * t3 + s0 * r4[g][r][0] + c6 * v50);
            atomicAdd(&accum[base + 32 + ln*3 + 1], sb * t3 + s0 * r4[g][r][1] + c6 * v51);
            atomicAdd(&accum[base + 32 + ln*3 + 2], sc * t3 + s0 * r4[g][r][2] + c6 * v52);
        }
}

// Per-node LN, v2: LDS-staged, coalesced global access (64 nodes / 256 threads).
__global__ __launch_bounds__(256)
void node_kernel(const float* __restrict__ node_attr,
                 const float* __restrict__ mean_shift,
                 const float* __restrict__ aw,
                 const float* __restrict__ ab,
                 const float* __restrict__ cnt,
                 float* __restrict__ out)
{
    __shared__ float sv[64 * 85];   // row stride 85: gcd(85,32)=1 -> conflict-free
    __shared__ float s_inv[64];
    const int tid = threadIdx.x;
    const int n0  = blockIdx.x * 64;

    if (tid < 64) {
        int n = n0 + tid;
        s_inv[tid] = (n < N_NODES) ? 1.0f / fmaxf(cnt[n], 1.0f) : 0.0f;
    }
    __syncthreads();

    #pragma unroll
    for (int i = 0; i < 20; ++i) {      // coalesced load + mean-div + residual
        int idx = tid + i * 256;
        int r = idx / 80, cch = idx % 80;
        int n = n0 + r;
        if (n < N_NODES) {
            float o = out[(size_t)n * 80 + cch];
            float a = node_attr[(size_t)n * 80 + cch];
            sv[r * 85 + cch] = o * s_inv[r] + a;
        }
    }
    __syncthreads();

    if (tid < 64 && n0 + tid < N_NODES) {
        float v[80];
        const float* sp = sv + tid * 85;
        #pragma unroll
        for (int k = 0; k < 80; ++k) v[k] = sp[k];

        float m0 = 0.f;
        #pragma unroll
        for (int u = 0; u < 32; ++u) m0 += v[u];
        m0 *= (1.0f / 32.0f);
        float n0v = 0.f;
        #pragma unroll
        for (int u = 0; u < 32; ++u) {
            float f = v[u] - m0 * mean_shift[u];
            v[u] = f;
            n0v += f * f;
        }
        n0v = rsqrtf(n0v * (1.0f / 32.0f) + EPS_LN);
        #pragma unroll
        for (int u = 0; u < 32; ++u) v[u] = v[u] * (n0v * aw[u]) + ab[u];

        float m1[3] = {0.f, 0.f, 0.f};
        #pragma unroll
        for (int u = 0; u < 16; ++u)
            #pragma unroll
            for (int i = 0; i < 3; ++i) m1[i] += v[32 + u*3 + i];
        #pragma unroll
        for (int i = 0; i < 3; ++i) m1[i] *= (1.0f / 16.0f);
        float n1 = 0.f;
        #pragma unroll
        for (int u = 0; u < 16; ++u)
            #pragma unroll
            for (int i = 0; i < 3; ++i) {
                float f = v[32 + u*3 + i] - m1[i] * mean_shift[32 + u];
                v[32 + u*3 + i] = f;
                n1 += f * f;
            }
        n1 = rsqrtf(n1 * (1.0f / 48.0f) + EPS_LN);
        #pragma unroll
        for (int u = 0; u < 16; ++u)
            #pragma unroll
            for (int i = 0; i < 3; ++i)
                v[32 + u*3 + i] *= (n1 * aw[32 + u]);

        float* wp = sv + tid * 85;
        #pragma unroll
        for (int k = 0; k < 80; ++k) wp[k] = v[k];
    }
    __syncthreads();

    #pragma unroll
    for (int i = 0; i < 20; ++i) {      // coalesced store
        int idx = tid + i * 256;
        int r = idx / 80, cch = idx % 80;
        int n = n0 + r;
        if (n < N_NODES) out[(size_t)n * 80 + cch] = sv[r * 85 + cch];
    }
}

extern "C" void kernel_launch(void* const* d_in, const int* in_sizes, int n_in,
                              void* d_out, int out_size, void* d_ws, size_t ws_size,
                              hipStream_t stream) {
    const float* node_attr  = (const float*)d_in[0];
    const float* edge_attr  = (const float*)d_in[1];
    const float* edge_sh    = (const float*)d_in[2];
    const float* fc_w1      = (const float*)d_in[3];
    const float* fc_b1      = (const float*)d_in[4];
    const float* fc_w2      = (const float*)d_in[5];
    const float* fc_b2      = (const float*)d_in[6];
    const float* mean_shift = (const float*)d_in[7];
    const float* aw         = (const float*)d_in[8];
    const float* ab         = (const float*)d_in[9];
    const int*   edge_index = (const int*)d_in[10];
    float* out = (float*)d_out;

    short* w1f = (short*)((char*)d_ws + W1F_OFF);
    short* w2f = (short*)((char*)d_ws + W2F_OFF);
    float* cnt = (float*)((char*)d_ws + CNT_OFF);

    (void)hipMemsetAsync(d_out, 0, (size_t)N_NODES * 80 * sizeof(float), stream);

    prep_kernel<<<(2048 + 40960 + 255) / 256, 256, 0, stream>>>(fc_w1, fc_w2, w1f, w2f, cnt);
    edge_kernel<<<EBLK, 256, 0, stream>>>(node_attr, edge_attr, edge_sh,
                                          fc_b1, fc_b2, edge_index,
                                          w1f, w2f, out, cnt);
    node_kernel<<<(N_NODES + 63) / 64, 256, 0, stream>>>(node_attr, mean_shift,
                                                         aw, ab, cnt, out);
}